// Round 1
// baseline (2740.151 us; speedup 1.0000x reference)
//
#include <hip/hip_runtime.h>

#define N_NODES  100000
#define N_EDGES  1600000
#define D        128

// ---------------------------------------------------------------------------
// Scatter: AH[src[e]][:] += val[e] * H[dst[e]][:]
// 32 lanes per edge, each lane owns 4 contiguous floats (one float4 gather,
// four HW f32 atomics). unsafeAtomicAdd -> global_atomic_add_f32 (no CAS loop).
// ---------------------------------------------------------------------------
__global__ __launch_bounds__(256) void scatter_kernel(
    const float* __restrict__ H, const float* __restrict__ vals,
    const int* __restrict__ src, const int* __restrict__ dst,
    float* __restrict__ AH)
{
    long gid = (long)blockIdx.x * blockDim.x + threadIdx.x;
    int e = (int)(gid >> 5);
    int l = (int)(gid & 31);
    if (e >= N_EDGES) return;
    int s = src[e];
    int d = dst[e];
    float v = vals[e];
    const float4 h = *reinterpret_cast<const float4*>(H + (size_t)d * D + l * 4);
    float* outp = AH + (size_t)s * D + l * 4;
    unsafeAtomicAdd(outp + 0, v * h.x);
    unsafeAtomicAdd(outp + 1, v * h.y);
    unsafeAtomicAdd(outp + 2, v * h.z);
    unsafeAtomicAdd(outp + 3, v * h.w);
}

// ---------------------------------------------------------------------------
// out = relu(AH @ W + b)   [100000,128] @ [128,128]
// BM=64 rows/block, BN=128 (full), BK=32. 256 threads: 8 (ty, row groups) x
// 32 (tx, col groups). Each thread: 8 rows x 4 cols register tile.
// ---------------------------------------------------------------------------
__global__ __launch_bounds__(256) void gemm_bias_relu(
    const float* __restrict__ A, const float* __restrict__ W,
    const float* __restrict__ b, float* __restrict__ out)
{
    __shared__ float As[64 * 32];    // 8 KB
    __shared__ float Ws[32 * 128];   // 16 KB

    const int tid  = threadIdx.x;
    const int ty   = tid >> 5;       // 0..7
    const int tx   = tid & 31;       // 0..31
    const int row0 = ty * 8;         // local row base
    const int col0 = tx * 4;         // col base
    const int blockRow = blockIdx.x * 64;

    float acc[8][4] = {};

    for (int kt = 0; kt < 128; kt += 32) {
        // stage A tile: 64 rows x 32 k  = 512 float4, 2 per thread
#pragma unroll
        for (int j = 0; j < 2; ++j) {
            int idx = j * 256 + tid;          // 0..511
            int r   = idx >> 3;               // 0..63
            int f   = idx & 7;                // float4 slot within row
            int grow = blockRow + r;
            if (grow >= N_NODES) grow = N_NODES - 1;   // clamp (dup read, never stored)
            float4 av = *reinterpret_cast<const float4*>(A + (size_t)grow * D + kt + f * 4);
            *reinterpret_cast<float4*>(&As[r * 32 + f * 4]) = av;
        }
        // stage W tile: 32 k x 128 cols = 1024 float4, 4 per thread
#pragma unroll
        for (int j = 0; j < 4; ++j) {
            int idx = j * 256 + tid;          // 0..1023
            int r   = idx >> 5;               // 0..31
            int f   = idx & 31;
            float4 wv = *reinterpret_cast<const float4*>(W + (size_t)(kt + r) * D + f * 4);
            *reinterpret_cast<float4*>(&Ws[r * 128 + f * 4]) = wv;
        }
        __syncthreads();

#pragma unroll
        for (int k4 = 0; k4 < 8; ++k4) {
            float4 av[8];
#pragma unroll
            for (int r = 0; r < 8; ++r)
                av[r] = *reinterpret_cast<const float4*>(&As[(row0 + r) * 32 + k4 * 4]);
#pragma unroll
            for (int kk = 0; kk < 4; ++kk) {
                float4 wv = *reinterpret_cast<const float4*>(&Ws[(k4 * 4 + kk) * 128 + col0]);
#pragma unroll
                for (int r = 0; r < 8; ++r) {
                    float a = (&av[r].x)[kk];
                    acc[r][0] += a * wv.x;
                    acc[r][1] += a * wv.y;
                    acc[r][2] += a * wv.z;
                    acc[r][3] += a * wv.w;
                }
            }
        }
        __syncthreads();
    }

    const float4 bias = *reinterpret_cast<const float4*>(b + col0);
#pragma unroll
    for (int r = 0; r < 8; ++r) {
        int grow = blockRow + row0 + r;
        if (grow < N_NODES) {
            float4 o;
            o.x = fmaxf(acc[r][0] + bias.x, 0.f);
            o.y = fmaxf(acc[r][1] + bias.y, 0.f);
            o.z = fmaxf(acc[r][2] + bias.z, 0.f);
            o.w = fmaxf(acc[r][3] + bias.w, 0.f);
            *reinterpret_cast<float4*>(out + (size_t)grow * D + col0) = o;
        }
    }
}

extern "C" void kernel_launch(void* const* d_in, const int* in_sizes, int n_in,
                              void* d_out, int out_size, void* d_ws, size_t ws_size,
                              hipStream_t stream) {
    const float* H    = (const float*)d_in[0];
    const float* vals = (const float*)d_in[1];
    const float* W    = (const float*)d_in[2];
    const float* b    = (const float*)d_in[3];
    const int*   src  = (const int*)d_in[4];
    const int*   dst  = (const int*)d_in[5];
    float* out = (float*)d_out;
    float* AH  = (float*)d_ws;   // [N_NODES][D] f32 accumulator = 51.2 MB

    hipMemsetAsync(AH, 0, (size_t)N_NODES * D * sizeof(float), stream);

    // scatter: 32 threads per edge
    long total_threads = (long)N_EDGES * 32;
    int blocks = (int)((total_threads + 255) / 256);
    scatter_kernel<<<blocks, 256, 0, stream>>>(H, vals, src, dst, AH);

    // dense projection + bias + relu
    gemm_bias_relu<<<(N_NODES + 63) / 64, 256, 0, stream>>>(AH, W, b, out);
}

// Round 2
// 372.614 us; speedup vs baseline: 7.3539x; 7.3539x over previous
//
#include <hip/hip_runtime.h>

#define N_NODES  100000
#define N_EDGES  1600000
#define D        128
#define SCAN_CHUNK 1024                       // elements per scan block
#define SCAN_BLOCKS ((N_NODES + SCAN_CHUNK - 1) / SCAN_CHUNK)   // 98

// ---------------------------------------------------------------------------
// 1) histogram of src
// ---------------------------------------------------------------------------
__global__ __launch_bounds__(256) void hist_kernel(
    const int* __restrict__ src, int* __restrict__ counts)
{
    int e = blockIdx.x * 256 + threadIdx.x;
    if (e >= N_EDGES) return;
    atomicAdd(&counts[src[e]], 1);
}

// ---------------------------------------------------------------------------
// 2) exclusive scan, 3 kernels. scan1: per-block (1024 elems) exclusive scan
//    + block total. 256 threads, 4 elems/thread.
// ---------------------------------------------------------------------------
__global__ __launch_bounds__(256) void scan1_kernel(
    const int* __restrict__ counts, int* __restrict__ offsets,
    int* __restrict__ blockSums)
{
    __shared__ int waveTot[4];
    const int b = blockIdx.x, tid = threadIdx.x;
    const int lane = tid & 63, wid = tid >> 6;
    const int base = b * SCAN_CHUNK + tid * 4;
    int v[4];
#pragma unroll
    for (int i = 0; i < 4; ++i) {
        int idx = base + i;
        v[i] = (idx < N_NODES) ? counts[idx] : 0;
    }
    int s = v[0] + v[1] + v[2] + v[3];
    int x = s;                                    // inclusive wave scan
    for (int off = 1; off < 64; off <<= 1) {
        int y = __shfl_up(x, off);
        if (lane >= off) x += y;
    }
    if (lane == 63) waveTot[wid] = x;
    __syncthreads();
    int wofs = 0;
    for (int w = 0; w < 4; ++w) if (w < wid) wofs += waveTot[w];
    int run = wofs + x - s;                       // exclusive prefix of this thread's group
#pragma unroll
    for (int i = 0; i < 4; ++i) {
        int idx = base + i;
        if (idx < N_NODES) offsets[idx] = run;
        run += v[i];
    }
    if (tid == 255) blockSums[b] = wofs + x;      // block total
}

__global__ void scan2_kernel(const int* __restrict__ bs, int* __restrict__ bss)
{
    __shared__ int tmp[128];
    int tid = threadIdx.x;
    int v = (tid < SCAN_BLOCKS) ? bs[tid] : 0;
    tmp[tid] = v;
    __syncthreads();
    for (int off = 1; off < 128; off <<= 1) {
        int y = (tid >= off) ? tmp[tid - off] : 0;
        __syncthreads();
        tmp[tid] += y;
        __syncthreads();
    }
    bss[tid] = tmp[tid] - v;                      // exclusive
}

__global__ __launch_bounds__(256) void scan3_kernel(
    int* __restrict__ offsets, const int* __restrict__ bss)
{
    int b = blockIdx.x;
    int add = bss[b];
    int base = b * SCAN_CHUNK + threadIdx.x;
#pragma unroll
    for (int i = 0; i < 4; ++i) {
        int idx = base + i * 256;
        if (idx < N_NODES) offsets[idx] += add;
    }
    if (b == 0 && threadIdx.x == 0) offsets[N_NODES] = N_EDGES;
}

// ---------------------------------------------------------------------------
// 3) bucket-fill: reorder (dst, val) by src
// ---------------------------------------------------------------------------
__global__ __launch_bounds__(256) void fill_kernel(
    const int* __restrict__ src, const int* __restrict__ dst,
    const float* __restrict__ vals, const int* __restrict__ offsets,
    int* __restrict__ cursor, int* __restrict__ sdst, float* __restrict__ sval)
{
    int e = blockIdx.x * 256 + threadIdx.x;
    if (e >= N_EDGES) return;
    int s = src[e];
    int pos = offsets[s] + atomicAdd(&cursor[s], 1);
    sdst[pos] = dst[e];
    sval[pos] = vals[e];
}

// ---------------------------------------------------------------------------
// 4) gather: one wave per node. AH[n] = sum_j val[j] * H[dst[j]]
//    lane owns 2 floats of the 128-wide row; 2-edge unroll for MLP.
// ---------------------------------------------------------------------------
__global__ __launch_bounds__(256) void gather_kernel(
    const float* __restrict__ H, const int* __restrict__ offs,
    const int* __restrict__ sdst, const float* __restrict__ sval,
    float* __restrict__ AH)
{
    const int wid  = threadIdx.x >> 6;
    const int lane = threadIdx.x & 63;
    const int node = blockIdx.x * 4 + wid;
    if (node >= N_NODES) return;
    const int beg = offs[node], end = offs[node + 1];
    float ax = 0.f, ay = 0.f, bx = 0.f, by = 0.f;
    int j = beg;
    for (; j + 2 <= end; j += 2) {
        int d0 = sdst[j], d1 = sdst[j + 1];
        float v0 = sval[j], v1 = sval[j + 1];
        float2 h0 = *reinterpret_cast<const float2*>(H + (size_t)d0 * D + lane * 2);
        float2 h1 = *reinterpret_cast<const float2*>(H + (size_t)d1 * D + lane * 2);
        ax += v0 * h0.x; ay += v0 * h0.y;
        bx += v1 * h1.x; by += v1 * h1.y;
    }
    if (j < end) {
        int d = sdst[j];
        float v = sval[j];
        float2 h = *reinterpret_cast<const float2*>(H + (size_t)d * D + lane * 2);
        ax += v * h.x; ay += v * h.y;
    }
    float2 o;
    o.x = ax + bx;
    o.y = ay + by;
    *reinterpret_cast<float2*>(AH + (size_t)node * D + lane * 2) = o;
}

// ---------------------------------------------------------------------------
// 5) out = relu(AH @ W + b)  (unchanged from R1)
// ---------------------------------------------------------------------------
__global__ __launch_bounds__(256) void gemm_bias_relu(
    const float* __restrict__ A, const float* __restrict__ W,
    const float* __restrict__ b, float* __restrict__ out)
{
    __shared__ float As[64 * 32];
    __shared__ float Ws[32 * 128];

    const int tid  = threadIdx.x;
    const int ty   = tid >> 5;
    const int tx   = tid & 31;
    const int row0 = ty * 8;
    const int col0 = tx * 4;
    const int blockRow = blockIdx.x * 64;

    float acc[8][4] = {};

    for (int kt = 0; kt < 128; kt += 32) {
#pragma unroll
        for (int j = 0; j < 2; ++j) {
            int idx = j * 256 + tid;
            int r   = idx >> 3;
            int f   = idx & 7;
            int grow = blockRow + r;
            if (grow >= N_NODES) grow = N_NODES - 1;
            float4 av = *reinterpret_cast<const float4*>(A + (size_t)grow * D + kt + f * 4);
            *reinterpret_cast<float4*>(&As[r * 32 + f * 4]) = av;
        }
#pragma unroll
        for (int j = 0; j < 4; ++j) {
            int idx = j * 256 + tid;
            int r   = idx >> 5;
            int f   = idx & 31;
            float4 wv = *reinterpret_cast<const float4*>(W + (size_t)(kt + r) * D + f * 4);
            *reinterpret_cast<float4*>(&Ws[r * 128 + f * 4]) = wv;
        }
        __syncthreads();

#pragma unroll
        for (int k4 = 0; k4 < 8; ++k4) {
            float4 av[8];
#pragma unroll
            for (int r = 0; r < 8; ++r)
                av[r] = *reinterpret_cast<const float4*>(&As[(row0 + r) * 32 + k4 * 4]);
#pragma unroll
            for (int kk = 0; kk < 4; ++kk) {
                float4 wv = *reinterpret_cast<const float4*>(&Ws[(k4 * 4 + kk) * 128 + col0]);
#pragma unroll
                for (int r = 0; r < 8; ++r) {
                    float a = (&av[r].x)[kk];
                    acc[r][0] += a * wv.x;
                    acc[r][1] += a * wv.y;
                    acc[r][2] += a * wv.z;
                    acc[r][3] += a * wv.w;
                }
            }
        }
        __syncthreads();
    }

    const float4 bias = *reinterpret_cast<const float4*>(b + col0);
#pragma unroll
    for (int r = 0; r < 8; ++r) {
        int grow = blockRow + row0 + r;
        if (grow < N_NODES) {
            float4 o;
            o.x = fmaxf(acc[r][0] + bias.x, 0.f);
            o.y = fmaxf(acc[r][1] + bias.y, 0.f);
            o.z = fmaxf(acc[r][2] + bias.z, 0.f);
            o.w = fmaxf(acc[r][3] + bias.w, 0.f);
            *reinterpret_cast<float4*>(out + (size_t)grow * D + col0) = o;
        }
    }
}

extern "C" void kernel_launch(void* const* d_in, const int* in_sizes, int n_in,
                              void* d_out, int out_size, void* d_ws, size_t ws_size,
                              hipStream_t stream) {
    const float* H    = (const float*)d_in[0];
    const float* vals = (const float*)d_in[1];
    const float* W    = (const float*)d_in[2];
    const float* b    = (const float*)d_in[3];
    const int*   src  = (const int*)d_in[4];
    const int*   dst  = (const int*)d_in[5];
    float* out = (float*)d_out;

    // workspace layout (~65 MB)
    float* AH        = (float*)d_ws;                       // 12.8M f32
    int*   counts    = (int*)(AH + (size_t)N_NODES * D);   // 100000
    int*   cursor    = counts + N_NODES;                   // 100000
    int*   offsets   = cursor + N_NODES;                   // 100001 (+1 pad)
    int*   blockSums = offsets + N_NODES + 2;              // 128
    int*   blockSumsS= blockSums + 128;                    // 128
    int*   sdst      = blockSumsS + 128;                   // 1.6M
    float* sval      = (float*)(sdst + N_EDGES);           // 1.6M

    // zero counts + cursor (contiguous)
    hipMemsetAsync(counts, 0, 2 * (size_t)N_NODES * sizeof(int), stream);

    hist_kernel<<<(N_EDGES + 255) / 256, 256, 0, stream>>>(src, counts);
    scan1_kernel<<<SCAN_BLOCKS, 256, 0, stream>>>(counts, offsets, blockSums);
    scan2_kernel<<<1, 128, 0, stream>>>(blockSums, blockSumsS);
    scan3_kernel<<<SCAN_BLOCKS, 256, 0, stream>>>(offsets, blockSumsS);
    fill_kernel<<<(N_EDGES + 255) / 256, 256, 0, stream>>>(src, dst, vals, offsets,
                                                           cursor, sdst, sval);
    gather_kernel<<<(N_NODES + 3) / 4, 256, 0, stream>>>(H, offsets, sdst, sval, AH);
    gemm_bias_relu<<<(N_NODES + 63) / 64, 256, 0, stream>>>(AH, W, b, out);
}

// Round 3
// 291.200 us; speedup vs baseline: 9.4099x; 1.2796x over previous
//
#include <hip/hip_runtime.h>

#define N_NODES  100000
#define N_EDGES  1600000
#define D        128
#define SCAN_CHUNK 1024
#define SCAN_BLOCKS ((N_NODES + SCAN_CHUNK - 1) / SCAN_CHUNK)   // 98

// f32 -> bf16 (round-to-nearest-even), packed helpers
__device__ __forceinline__ unsigned short f2bf(float x) {
    unsigned u = __float_as_uint(x);
    u += 0x7fffu + ((u >> 16) & 1u);
    return (unsigned short)(u >> 16);
}

// ---------------------------------------------------------------------------
// 1) histogram of src
// ---------------------------------------------------------------------------
__global__ __launch_bounds__(256) void hist_kernel(
    const int* __restrict__ src, int* __restrict__ counts)
{
    int e = blockIdx.x * 256 + threadIdx.x;
    if (e >= N_EDGES) return;
    atomicAdd(&counts[src[e]], 1);
}

// ---------------------------------------------------------------------------
// 2) exclusive scan (3 kernels)
// ---------------------------------------------------------------------------
__global__ __launch_bounds__(256) void scan1_kernel(
    const int* __restrict__ counts, int* __restrict__ offsets,
    int* __restrict__ blockSums)
{
    __shared__ int waveTot[4];
    const int b = blockIdx.x, tid = threadIdx.x;
    const int lane = tid & 63, wid = tid >> 6;
    const int base = b * SCAN_CHUNK + tid * 4;
    int v[4];
#pragma unroll
    for (int i = 0; i < 4; ++i) {
        int idx = base + i;
        v[i] = (idx < N_NODES) ? counts[idx] : 0;
    }
    int s = v[0] + v[1] + v[2] + v[3];
    int x = s;
    for (int off = 1; off < 64; off <<= 1) {
        int y = __shfl_up(x, off);
        if (lane >= off) x += y;
    }
    if (lane == 63) waveTot[wid] = x;
    __syncthreads();
    int wofs = 0;
    for (int w = 0; w < 4; ++w) if (w < wid) wofs += waveTot[w];
    int run = wofs + x - s;
#pragma unroll
    for (int i = 0; i < 4; ++i) {
        int idx = base + i;
        if (idx < N_NODES) offsets[idx] = run;
        run += v[i];
    }
    if (tid == 255) blockSums[b] = wofs + x;
}

__global__ void scan2_kernel(const int* __restrict__ bs, int* __restrict__ bss)
{
    __shared__ int tmp[128];
    int tid = threadIdx.x;
    int v = (tid < SCAN_BLOCKS) ? bs[tid] : 0;
    tmp[tid] = v;
    __syncthreads();
    for (int off = 1; off < 128; off <<= 1) {
        int y = (tid >= off) ? tmp[tid - off] : 0;
        __syncthreads();
        tmp[tid] += y;
        __syncthreads();
    }
    bss[tid] = tmp[tid] - v;
}

__global__ __launch_bounds__(256) void scan3_kernel(
    int* __restrict__ offsets, const int* __restrict__ bss)
{
    int b = blockIdx.x;
    int add = bss[b];
    int base = b * SCAN_CHUNK + threadIdx.x;
#pragma unroll
    for (int i = 0; i < 4; ++i) {
        int idx = base + i * 256;
        if (idx < N_NODES) offsets[idx] += add;
    }
    if (b == 0 && threadIdx.x == 0) offsets[N_NODES] = N_EDGES;
}

// ---------------------------------------------------------------------------
// 3) bucket-fill: single packed 8B store per edge
// ---------------------------------------------------------------------------
__global__ __launch_bounds__(256) void fill_kernel(
    const int* __restrict__ src, const int* __restrict__ dst,
    const float* __restrict__ vals, const int* __restrict__ offsets,
    int* __restrict__ cursor, int2* __restrict__ sedge)
{
    int e = blockIdx.x * 256 + threadIdx.x;
    if (e >= N_EDGES) return;
    int s = src[e];
    int pos = offsets[s] + atomicAdd(&cursor[s], 1);
    int2 p;
    p.x = dst[e];
    p.y = __float_as_int(vals[e]);
    sedge[pos] = p;
}

// ---------------------------------------------------------------------------
// 4) HW = H @ W, stored bf16. BM=64, BN=128, BK=32, 256 thr, 8x4 reg tile.
// ---------------------------------------------------------------------------
__global__ __launch_bounds__(256) void gemm_hw_bf16(
    const float* __restrict__ A, const float* __restrict__ W,
    unsigned short* __restrict__ HWb)
{
    __shared__ float As[64 * 32];
    __shared__ float Ws[32 * 128];

    const int tid  = threadIdx.x;
    const int ty   = tid >> 5;
    const int tx   = tid & 31;
    const int row0 = ty * 8;
    const int col0 = tx * 4;
    const int blockRow = blockIdx.x * 64;

    float acc[8][4] = {};

    for (int kt = 0; kt < 128; kt += 32) {
#pragma unroll
        for (int j = 0; j < 2; ++j) {
            int idx = j * 256 + tid;
            int r   = idx >> 3;
            int f   = idx & 7;
            int grow = blockRow + r;
            if (grow >= N_NODES) grow = N_NODES - 1;
            float4 av = *reinterpret_cast<const float4*>(A + (size_t)grow * D + kt + f * 4);
            *reinterpret_cast<float4*>(&As[r * 32 + f * 4]) = av;
        }
#pragma unroll
        for (int j = 0; j < 4; ++j) {
            int idx = j * 256 + tid;
            int r   = idx >> 5;
            int f   = idx & 31;
            float4 wv = *reinterpret_cast<const float4*>(W + (size_t)(kt + r) * D + f * 4);
            *reinterpret_cast<float4*>(&Ws[r * 128 + f * 4]) = wv;
        }
        __syncthreads();

#pragma unroll
        for (int k4 = 0; k4 < 8; ++k4) {
            float4 av[8];
#pragma unroll
            for (int r = 0; r < 8; ++r)
                av[r] = *reinterpret_cast<const float4*>(&As[(row0 + r) * 32 + k4 * 4]);
#pragma unroll
            for (int kk = 0; kk < 4; ++kk) {
                float4 wv = *reinterpret_cast<const float4*>(&Ws[(k4 * 4 + kk) * 128 + col0]);
#pragma unroll
                for (int r = 0; r < 8; ++r) {
                    float a = (&av[r].x)[kk];
                    acc[r][0] += a * wv.x;
                    acc[r][1] += a * wv.y;
                    acc[r][2] += a * wv.z;
                    acc[r][3] += a * wv.w;
                }
            }
        }
        __syncthreads();
    }

#pragma unroll
    for (int r = 0; r < 8; ++r) {
        int grow = blockRow + row0 + r;
        if (grow < N_NODES) {
            ushort4 o;
            o.x = f2bf(acc[r][0]);
            o.y = f2bf(acc[r][1]);
            o.z = f2bf(acc[r][2]);
            o.w = f2bf(acc[r][3]);
            *reinterpret_cast<ushort4*>(HWb + (size_t)grow * D + col0) = o;
        }
    }
}

// ---------------------------------------------------------------------------
// 5) out[n] = relu( sum_j val[j] * HWb[dst[j]] + b )
//    one wave per node; lane owns 2 columns (one dword of bf16x2 per edge).
// ---------------------------------------------------------------------------
__global__ __launch_bounds__(256) void gather_out_kernel(
    const unsigned short* __restrict__ HWb, const int* __restrict__ offs,
    const int2* __restrict__ sedge, const float* __restrict__ b,
    float* __restrict__ out)
{
    const int wid  = threadIdx.x >> 6;
    const int lane = threadIdx.x & 63;
    const int node = blockIdx.x * 4 + wid;
    if (node >= N_NODES) return;
    const int beg = offs[node], end = offs[node + 1];

    float a0x = 0.f, a0y = 0.f, a1x = 0.f, a1y = 0.f;
    float a2x = 0.f, a2y = 0.f, a3x = 0.f, a3y = 0.f;

    int j = beg;
    for (; j + 4 <= end; j += 4) {
        int4 e01 = *reinterpret_cast<const int4*>(&sedge[j]);
        int4 e23 = *reinterpret_cast<const int4*>(&sedge[j + 2]);
        unsigned u0 = *reinterpret_cast<const unsigned*>(HWb + (size_t)e01.x * D + lane * 2);
        unsigned u1 = *reinterpret_cast<const unsigned*>(HWb + (size_t)e01.z * D + lane * 2);
        unsigned u2 = *reinterpret_cast<const unsigned*>(HWb + (size_t)e23.x * D + lane * 2);
        unsigned u3 = *reinterpret_cast<const unsigned*>(HWb + (size_t)e23.z * D + lane * 2);
        float v0 = __int_as_float(e01.y), v1 = __int_as_float(e01.w);
        float v2 = __int_as_float(e23.y), v3 = __int_as_float(e23.w);
        a0x += v0 * __uint_as_float(u0 << 16);
        a0y += v0 * __uint_as_float(u0 & 0xffff0000u);
        a1x += v1 * __uint_as_float(u1 << 16);
        a1y += v1 * __uint_as_float(u1 & 0xffff0000u);
        a2x += v2 * __uint_as_float(u2 << 16);
        a2y += v2 * __uint_as_float(u2 & 0xffff0000u);
        a3x += v3 * __uint_as_float(u3 << 16);
        a3y += v3 * __uint_as_float(u3 & 0xffff0000u);
    }
    for (; j < end; ++j) {
        int2 e = sedge[j];
        unsigned u = *reinterpret_cast<const unsigned*>(HWb + (size_t)e.x * D + lane * 2);
        float v = __int_as_float(e.y);
        a0x += v * __uint_as_float(u << 16);
        a0y += v * __uint_as_float(u & 0xffff0000u);
    }

    float2 bias = *reinterpret_cast<const float2*>(b + lane * 2);
    float2 o;
    o.x = fmaxf((a0x + a1x) + (a2x + a3x) + bias.x, 0.f);
    o.y = fmaxf((a0y + a1y) + (a2y + a3y) + bias.y, 0.f);
    *reinterpret_cast<float2*>(out + (size_t)node * D + lane * 2) = o;
}

extern "C" void kernel_launch(void* const* d_in, const int* in_sizes, int n_in,
                              void* d_out, int out_size, void* d_ws, size_t ws_size,
                              hipStream_t stream) {
    const float* H    = (const float*)d_in[0];
    const float* vals = (const float*)d_in[1];
    const float* W    = (const float*)d_in[2];
    const float* b    = (const float*)d_in[3];
    const int*   src  = (const int*)d_in[4];
    const int*   dst  = (const int*)d_in[5];
    float* out = (float*)d_out;

    // workspace layout (~40 MB)
    unsigned short* HWb = (unsigned short*)d_ws;                 // 12.8M bf16 = 25.6 MB
    int*  counts    = (int*)(HWb + (size_t)N_NODES * D);         // 100000
    int*  cursor    = counts + N_NODES;                          // 100000
    int*  offsets   = cursor + N_NODES;                          // 100001 (+pad)
    int*  blockSums = offsets + N_NODES + 2;                     // 128
    int*  blockSumsS= blockSums + 128;                           // 128
    int2* sedge     = (int2*)(blockSumsS + 128);                 // 1.6M int2 = 12.8 MB

    hipMemsetAsync(counts, 0, 2 * (size_t)N_NODES * sizeof(int), stream);

    hist_kernel<<<(N_EDGES + 255) / 256, 256, 0, stream>>>(src, counts);
    scan1_kernel<<<SCAN_BLOCKS, 256, 0, stream>>>(counts, offsets, blockSums);
    scan2_kernel<<<1, 128, 0, stream>>>(blockSums, blockSumsS);
    scan3_kernel<<<SCAN_BLOCKS, 256, 0, stream>>>(offsets, blockSumsS);
    fill_kernel<<<(N_EDGES + 255) / 256, 256, 0, stream>>>(src, dst, vals, offsets,
                                                           cursor, sedge);
    gemm_hw_bf16<<<(N_NODES + 63) / 64, 256, 0, stream>>>(H, W, HWb);
    gather_out_kernel<<<(N_NODES + 3) / 4, 256, 0, stream>>>(HWb, offsets, sedge, b, out);
}

// Round 4
// 198.994 us; speedup vs baseline: 13.7700x; 1.4634x over previous
//
#include <hip/hip_runtime.h>

#define N_NODES  100000
#define N_EDGES  1600000
#define D        128
#define NBUCK    782          // ceil(100000 / 128): coarse buckets of 128 nodes
#define HCHUNK   4096         // edges per WG in hist
#define FCHUNK   8192         // edges per WG in fill

// f32 -> bf16 (round-to-nearest-even)
__device__ __forceinline__ unsigned short f2bf(float x) {
    unsigned u = __float_as_uint(x);
    u += 0x7fffu + ((u >> 16) & 1u);
    return (unsigned short)(u >> 16);
}

// ---------------------------------------------------------------------------
// 1) coarse histogram (LDS-aggregated): counts[b] = #edges with src>>7 == b
// ---------------------------------------------------------------------------
__global__ __launch_bounds__(256) void hist_coarse(
    const int* __restrict__ src, int* __restrict__ counts)
{
    __shared__ int lh[NBUCK];
    const int t = threadIdx.x;
    for (int i = t; i < NBUCK; i += 256) lh[i] = 0;
    __syncthreads();
    const int e0 = blockIdx.x * HCHUNK;
    const int e1 = min(e0 + HCHUNK, N_EDGES);
    for (int e = e0 + t; e < e1; e += 256)
        atomicAdd(&lh[src[e] >> 7], 1);
    __syncthreads();
    for (int i = t; i < NBUCK; i += 256) {
        int c = lh[i];
        if (c) atomicAdd(&counts[i], c);
    }
}

// ---------------------------------------------------------------------------
// 2) exclusive scan of 782 coarse counts (single block, 256 thr x 4)
// ---------------------------------------------------------------------------
__global__ __launch_bounds__(256) void scan_coarse(
    const int* __restrict__ counts, int* __restrict__ coff)
{
    __shared__ int waveTot[4];
    const int tid = threadIdx.x;
    const int lane = tid & 63, wid = tid >> 6;
    const int base = tid * 4;
    int v[4];
#pragma unroll
    for (int i = 0; i < 4; ++i) {
        int idx = base + i;
        v[i] = (idx < NBUCK) ? counts[idx] : 0;
    }
    int s = v[0] + v[1] + v[2] + v[3];
    int x = s;
    for (int off = 1; off < 64; off <<= 1) {
        int y = __shfl_up(x, off);
        if (lane >= off) x += y;
    }
    if (lane == 63) waveTot[wid] = x;
    __syncthreads();
    int wofs = 0;
    for (int w = 0; w < 4; ++w) if (w < wid) wofs += waveTot[w];
    int run = wofs + x - s;
#pragma unroll
    for (int i = 0; i < 4; ++i) {
        int idx = base + i;
        if (idx <= NBUCK) coff[idx] = run;
        run += v[i];
    }
}

// ---------------------------------------------------------------------------
// 3) coarse fill (workgroup-aggregated): place packed edge into its bucket.
//    packed.x = dst | (src&127)<<17 ; packed.y = bits(val)
// ---------------------------------------------------------------------------
__global__ __launch_bounds__(256) void fill_coarse(
    const int* __restrict__ src, const int* __restrict__ dst,
    const float* __restrict__ vals, const int* __restrict__ coff,
    int* __restrict__ ccursor, int2* __restrict__ sedge_raw)
{
    __shared__ int lhist[NBUCK];
    __shared__ int lbase[NBUCK];
    const int t = threadIdx.x;
    for (int i = t; i < NBUCK; i += 256) lhist[i] = 0;
    __syncthreads();
    const int e0 = blockIdx.x * FCHUNK;
    const int e1 = min(e0 + FCHUNK, N_EDGES);
    // phase 1: local histogram
    for (int e = e0 + t; e < e1; e += 256)
        atomicAdd(&lhist[src[e] >> 7], 1);
    __syncthreads();
    // phase 2: reserve global ranges, reset local cursors
    for (int i = t; i < NBUCK; i += 256) {
        int c = lhist[i];
        lbase[i] = c ? atomicAdd(&ccursor[i], c) : 0;
        lhist[i] = 0;
    }
    __syncthreads();
    // phase 3: place
    for (int e = e0 + t; e < e1; e += 256) {
        int s = src[e];
        int bkt = s >> 7;
        int pos = coff[bkt] + lbase[bkt] + atomicAdd(&lhist[bkt], 1);
        int2 p;
        p.x = dst[e] | ((s & 127) << 17);
        p.y = __float_as_int(vals[e]);
        sedge_raw[pos] = p;
    }
}

// ---------------------------------------------------------------------------
// 4) per-bucket counting sort by src_low (7 bits) -> fully sorted CSR +
//    per-node offsets. One WG per bucket; LDS = 3 small arrays.
// ---------------------------------------------------------------------------
__global__ __launch_bounds__(256) void sort_bucket(
    const int* __restrict__ coff, const int2* __restrict__ sedge_raw,
    int2* __restrict__ sedge, int* __restrict__ offsets)
{
    __shared__ int h[128];      // per-node-in-bucket count, later cursor
    __shared__ int excl[128];   // exclusive prefix
    const int b = blockIdx.x;
    const int t = threadIdx.x;
    const int beg = coff[b], end = coff[b + 1];

    if (t < 128) h[t] = 0;
    __syncthreads();
    for (int j = beg + t; j < end; j += 256)
        atomicAdd(&h[(sedge_raw[j].x >> 17) & 127], 1);
    __syncthreads();
    // inclusive scan of h into excl (Hillis-Steele over 128 entries)
    if (t < 128) excl[t] = h[t];
    __syncthreads();
    for (int off = 1; off < 128; off <<= 1) {
        int y = 0;
        if (t < 128 && t >= off) y = excl[t - off];
        __syncthreads();
        if (t < 128) excl[t] += y;
        __syncthreads();
    }
    // exclusive prefix, per-node global offsets, reset cursors
    if (t < 128) {
        int ex = excl[t] - h[t];
        int node = b * 128 + t;
        if (node <= N_NODES) offsets[node] = beg + ex;
        excl[t] = ex;
        h[t] = 0;
    }
    __syncthreads();
    // place sorted, strip packing (keep only dst in .x)
    for (int j = beg + t; j < end; j += 256) {
        int2 e = sedge_raw[j];
        int r = (e.x >> 17) & 127;
        int pos = beg + excl[r] + atomicAdd(&h[r], 1);
        e.x &= 0x1FFFF;
        sedge[pos] = e;
    }
}

// ---------------------------------------------------------------------------
// 5) HW = H @ W, stored bf16 (unchanged from R3)
// ---------------------------------------------------------------------------
__global__ __launch_bounds__(256) void gemm_hw_bf16(
    const float* __restrict__ A, const float* __restrict__ W,
    unsigned short* __restrict__ HWb)
{
    __shared__ float As[64 * 32];
    __shared__ float Ws[32 * 128];

    const int tid  = threadIdx.x;
    const int ty   = tid >> 5;
    const int tx   = tid & 31;
    const int row0 = ty * 8;
    const int col0 = tx * 4;
    const int blockRow = blockIdx.x * 64;

    float acc[8][4] = {};

    for (int kt = 0; kt < 128; kt += 32) {
#pragma unroll
        for (int j = 0; j < 2; ++j) {
            int idx = j * 256 + tid;
            int r   = idx >> 3;
            int f   = idx & 7;
            int grow = blockRow + r;
            if (grow >= N_NODES) grow = N_NODES - 1;
            float4 av = *reinterpret_cast<const float4*>(A + (size_t)grow * D + kt + f * 4);
            *reinterpret_cast<float4*>(&As[r * 32 + f * 4]) = av;
        }
#pragma unroll
        for (int j = 0; j < 4; ++j) {
            int idx = j * 256 + tid;
            int r   = idx >> 5;
            int f   = idx & 31;
            float4 wv = *reinterpret_cast<const float4*>(W + (size_t)(kt + r) * D + f * 4);
            *reinterpret_cast<float4*>(&Ws[r * 128 + f * 4]) = wv;
        }
        __syncthreads();

#pragma unroll
        for (int k4 = 0; k4 < 8; ++k4) {
            float4 av[8];
#pragma unroll
            for (int r = 0; r < 8; ++r)
                av[r] = *reinterpret_cast<const float4*>(&As[(row0 + r) * 32 + k4 * 4]);
#pragma unroll
            for (int kk = 0; kk < 4; ++kk) {
                float4 wv = *reinterpret_cast<const float4*>(&Ws[(k4 * 4 + kk) * 128 + col0]);
#pragma unroll
                for (int r = 0; r < 8; ++r) {
                    float a = (&av[r].x)[kk];
                    acc[r][0] += a * wv.x;
                    acc[r][1] += a * wv.y;
                    acc[r][2] += a * wv.z;
                    acc[r][3] += a * wv.w;
                }
            }
        }
        __syncthreads();
    }

#pragma unroll
    for (int r = 0; r < 8; ++r) {
        int grow = blockRow + row0 + r;
        if (grow < N_NODES) {
            ushort4 o;
            o.x = f2bf(acc[r][0]);
            o.y = f2bf(acc[r][1]);
            o.z = f2bf(acc[r][2]);
            o.w = f2bf(acc[r][3]);
            *reinterpret_cast<ushort4*>(HWb + (size_t)grow * D + col0) = o;
        }
    }
}

// ---------------------------------------------------------------------------
// 6) out[n] = relu( sum_j val[j] * HWb[dst[j]] + b )  (unchanged from R3)
// ---------------------------------------------------------------------------
__global__ __launch_bounds__(256) void gather_out_kernel(
    const unsigned short* __restrict__ HWb, const int* __restrict__ offs,
    const int2* __restrict__ sedge, const float* __restrict__ b,
    float* __restrict__ out)
{
    const int wid  = threadIdx.x >> 6;
    const int lane = threadIdx.x & 63;
    const int node = blockIdx.x * 4 + wid;
    if (node >= N_NODES) return;
    const int beg = offs[node], end = offs[node + 1];

    float a0x = 0.f, a0y = 0.f, a1x = 0.f, a1y = 0.f;
    float a2x = 0.f, a2y = 0.f, a3x = 0.f, a3y = 0.f;

    int j = beg;
    for (; j + 4 <= end; j += 4) {
        int4 e01 = *reinterpret_cast<const int4*>(&sedge[j]);
        int4 e23 = *reinterpret_cast<const int4*>(&sedge[j + 2]);
        unsigned u0 = *reinterpret_cast<const unsigned*>(HWb + (size_t)e01.x * D + lane * 2);
        unsigned u1 = *reinterpret_cast<const unsigned*>(HWb + (size_t)e01.z * D + lane * 2);
        unsigned u2 = *reinterpret_cast<const unsigned*>(HWb + (size_t)e23.x * D + lane * 2);
        unsigned u3 = *reinterpret_cast<const unsigned*>(HWb + (size_t)e23.z * D + lane * 2);
        float v0 = __int_as_float(e01.y), v1 = __int_as_float(e01.w);
        float v2 = __int_as_float(e23.y), v3 = __int_as_float(e23.w);
        a0x += v0 * __uint_as_float(u0 << 16);
        a0y += v0 * __uint_as_float(u0 & 0xffff0000u);
        a1x += v1 * __uint_as_float(u1 << 16);
        a1y += v1 * __uint_as_float(u1 & 0xffff0000u);
        a2x += v2 * __uint_as_float(u2 << 16);
        a2y += v2 * __uint_as_float(u2 & 0xffff0000u);
        a3x += v3 * __uint_as_float(u3 << 16);
        a3y += v3 * __uint_as_float(u3 & 0xffff0000u);
    }
    for (; j < end; ++j) {
        int2 e = sedge[j];
        unsigned u = *reinterpret_cast<const unsigned*>(HWb + (size_t)e.x * D + lane * 2);
        float v = __int_as_float(e.y);
        a0x += v * __uint_as_float(u << 16);
        a0y += v * __uint_as_float(u & 0xffff0000u);
    }

    float2 bias = *reinterpret_cast<const float2*>(b + lane * 2);
    float2 o;
    o.x = fmaxf((a0x + a1x) + (a2x + a3x) + bias.x, 0.f);
    o.y = fmaxf((a0y + a1y) + (a2y + a3y) + bias.y, 0.f);
    *reinterpret_cast<float2*>(out + (size_t)node * D + lane * 2) = o;
}

extern "C" void kernel_launch(void* const* d_in, const int* in_sizes, int n_in,
                              void* d_out, int out_size, void* d_ws, size_t ws_size,
                              hipStream_t stream) {
    const float* H    = (const float*)d_in[0];
    const float* vals = (const float*)d_in[1];
    const float* W    = (const float*)d_in[2];
    const float* b    = (const float*)d_in[3];
    const int*   src  = (const int*)d_in[4];
    const int*   dst  = (const int*)d_in[5];
    float* out = (float*)d_out;

    // workspace layout (~51.6 MB)
    unsigned short* HWb = (unsigned short*)d_ws;                   // 25.6 MB
    int2* sedge_raw  = (int2*)(HWb + (size_t)N_NODES * D);         // 12.8 MB
    int2* sedge      = sedge_raw + N_EDGES;                        // 12.8 MB
    int*  counts     = (int*)(sedge + N_EDGES);                    // NBUCK
    int*  ccursor    = counts + NBUCK;                             // NBUCK
    int*  coff       = ccursor + NBUCK;                            // NBUCK+1
    int*  offsets    = coff + NBUCK + 2;                           // N_NODES+1

    // zero coarse counts + cursors (contiguous, 6.3 KB)
    hipMemsetAsync(counts, 0, 2 * (size_t)NBUCK * sizeof(int), stream);

    hist_coarse<<<(N_EDGES + HCHUNK - 1) / HCHUNK, 256, 0, stream>>>(src, counts);
    scan_coarse<<<1, 256, 0, stream>>>(counts, coff);
    fill_coarse<<<(N_EDGES + FCHUNK - 1) / FCHUNK, 256, 0, stream>>>(
        src, dst, vals, coff, ccursor, sedge_raw);
    sort_bucket<<<NBUCK, 256, 0, stream>>>(coff, sedge_raw, sedge, offsets);
    gemm_hw_bf16<<<(N_NODES + 63) / 64, 256, 0, stream>>>(H, W, HWb);
    gather_out_kernel<<<(N_NODES + 3) / 4, 256, 0, stream>>>(HWb, offsets, sedge, b, out);
}

// Round 5
// 157.938 us; speedup vs baseline: 17.3495x; 1.2599x over previous
//
#include <hip/hip_runtime.h>

#define N_NODES  100000
#define N_EDGES  1600000
#define D        128
#define NBUCK    782          // ceil(100000 / 128)
#define BCAP     3072         // bucket capacity (avg 2046, sigma ~45 -> 22 sigma margin)
#define OCAP     8192         // overflow backstop capacity
#define FCHUNK   8192         // edges per WG in fill

typedef __attribute__((ext_vector_type(8))) short bf16x8;
typedef __attribute__((ext_vector_type(4))) float f32x4;

// f32 -> bf16 (round-to-nearest-even)
__device__ __forceinline__ unsigned short f2bf(float x) {
    unsigned u = __float_as_uint(x);
    u += 0x7fffu + ((u >> 16) & 1u);
    return (unsigned short)(u >> 16);
}

// ---------------------------------------------------------------------------
// 0) pack W (f32 [128k][128n]) into B-fragment order for mfma_f32_16x16x32_bf16
//    frag idx: lane = g*16 + (n&15), g=(k>>3)&3, j=k&7, tile=(c= n>>4, ks= k>>5)
//    Wfrag[(((c*4+ks)*64)+lane)*8 + j]
// ---------------------------------------------------------------------------
__global__ __launch_bounds__(256) void wconvert(
    const float* __restrict__ W, unsigned short* __restrict__ Wfrag)
{
    int t = blockIdx.x * 256 + threadIdx.x;
    if (t >= 128 * 128) return;
    int k = t >> 7, n = t & 127;
    int c = n >> 4, cc = n & 15, ks = k >> 5, g = (k >> 3) & 3, j = k & 7;
    int lane = g * 16 + cc;
    Wfrag[(size_t)(((c * 4 + ks) * 64) + lane) * 8 + j] = f2bf(W[t]);
}

// ---------------------------------------------------------------------------
// 1) HW = H @ W via MFMA 16x16x32 bf16, output bf16.
//    Block = 256 thr (4 waves), 64 rows; wave owns 16 rows x 128 cols.
//    A frag: row = lane&15, k = ks*32 + (lane>>4)*8 + j  (loaded from H, cvt)
//    C/D:    row = (lane>>4)*4 + r, col = c*16 + (lane&15)   [m89-verified]
// ---------------------------------------------------------------------------
__global__ __launch_bounds__(256) void gemm_mfma(
    const float* __restrict__ H, const unsigned short* __restrict__ Wfrag,
    unsigned short* __restrict__ HWb)
{
    const int wid  = threadIdx.x >> 6;
    const int lane = threadIdx.x & 63;
    const int row16 = blockIdx.x * 64 + wid * 16;
    const int g = lane >> 4;

    int arow = row16 + (lane & 15);
    if (arow >= N_NODES) arow = N_NODES - 1;    // clamp (dup read, never stored)

    f32x4 acc[8];
#pragma unroll
    for (int c = 0; c < 8; ++c) acc[c] = (f32x4){0.f, 0.f, 0.f, 0.f};

#pragma unroll
    for (int ks = 0; ks < 4; ++ks) {
        const float* ap = H + (size_t)arow * D + ks * 32 + g * 8;
        float4 a0 = *reinterpret_cast<const float4*>(ap);
        float4 a1 = *reinterpret_cast<const float4*>(ap + 4);
        bf16x8 af;
        af[0] = (short)f2bf(a0.x); af[1] = (short)f2bf(a0.y);
        af[2] = (short)f2bf(a0.z); af[3] = (short)f2bf(a0.w);
        af[4] = (short)f2bf(a1.x); af[5] = (short)f2bf(a1.y);
        af[6] = (short)f2bf(a1.z); af[7] = (short)f2bf(a1.w);
#pragma unroll
        for (int c = 0; c < 8; ++c) {
            bf16x8 bf = *reinterpret_cast<const bf16x8*>(
                Wfrag + (size_t)((c * 4 + ks) * 64 + lane) * 8);
            acc[c] = __builtin_amdgcn_mfma_f32_16x16x32_bf16(af, bf, acc[c], 0, 0, 0);
        }
    }

#pragma unroll
    for (int c = 0; c < 8; ++c) {
#pragma unroll
        for (int r = 0; r < 4; ++r) {
            int orow = row16 + g * 4 + r;
            if (orow < N_NODES)
                HWb[(size_t)orow * D + c * 16 + (lane & 15)] = f2bf(acc[c][r]);
        }
    }
}

// ---------------------------------------------------------------------------
// 2) fill fixed-stride buckets (WG-aggregated reservation, no global hist/scan)
//    packed.x = dst | (src&127)<<17 ; packed.y = bits(val)
// ---------------------------------------------------------------------------
__global__ __launch_bounds__(256) void fill_bucket(
    const int* __restrict__ src, const int* __restrict__ dst,
    const float* __restrict__ vals, int* __restrict__ ccursor,
    int2* __restrict__ sedge_raw, int4* __restrict__ oflow,
    int* __restrict__ oflow_cnt)
{
    __shared__ int lhist[NBUCK];
    __shared__ int lbase[NBUCK];
    const int t = threadIdx.x;
    for (int i = t; i < NBUCK; i += 256) lhist[i] = 0;
    __syncthreads();
    const int e0 = blockIdx.x * FCHUNK;
    const int e1 = min(e0 + FCHUNK, N_EDGES);
    for (int e = e0 + t; e < e1; e += 256)
        atomicAdd(&lhist[src[e] >> 7], 1);
    __syncthreads();
    for (int i = t; i < NBUCK; i += 256) {
        int c = lhist[i];
        lbase[i] = c ? atomicAdd(&ccursor[i], c) : 0;
        lhist[i] = 0;
    }
    __syncthreads();
    for (int e = e0 + t; e < e1; e += 256) {
        int s = src[e];
        int bkt = s >> 7;
        int pos = lbase[bkt] + atomicAdd(&lhist[bkt], 1);
        if (pos < BCAP) {
            int2 p;
            p.x = dst[e] | ((s & 127) << 17);
            p.y = __float_as_int(vals[e]);
            sedge_raw[(size_t)bkt * BCAP + pos] = p;
        } else {
            int oc = atomicAdd(oflow_cnt, 1);
            if (oc < OCAP) oflow[oc] = make_int4(s, dst[e], __float_as_int(vals[e]), 0);
        }
    }
}

// ---------------------------------------------------------------------------
// 3) fused counting-sort (into LDS) + gather + bias + relu. One WG per bucket.
// ---------------------------------------------------------------------------
__global__ __launch_bounds__(256) void sort_gather(
    const unsigned short* __restrict__ HWb, const int2* __restrict__ sedge_raw,
    const int* __restrict__ ccursor, const int4* __restrict__ oflow,
    const int* __restrict__ oflow_cnt, const float* __restrict__ bias,
    float* __restrict__ out)
{
    __shared__ int2 eLds[BCAP];     // 24 KB
    __shared__ int h[128];          // per-node counts
    __shared__ int ex[128];         // exclusive prefix
    __shared__ int cur[128];        // placement cursors
    const int bkt = blockIdx.x;
    const int t = threadIdx.x;
    const size_t base = (size_t)bkt * BCAP;
    const int cnt = min(ccursor[bkt], BCAP);

    if (t < 128) h[t] = 0;
    __syncthreads();
    // pass 1: histogram from global
    for (int j = t; j < cnt; j += 256)
        atomicAdd(&h[(sedge_raw[base + j].x >> 17) & 127], 1);
    __syncthreads();
    // scan (Hillis-Steele over 128)
    if (t < 128) ex[t] = h[t];
    __syncthreads();
    for (int off = 1; off < 128; off <<= 1) {
        int y = 0;
        if (t < 128 && t >= off) y = ex[t - off];
        __syncthreads();
        if (t < 128) ex[t] += y;
        __syncthreads();
    }
    if (t < 128) { ex[t] -= h[t]; cur[t] = 0; }
    __syncthreads();
    // pass 2: place sorted into LDS (strip src bits)
    for (int j = t; j < cnt; j += 256) {
        int2 e = sedge_raw[base + j];
        int r = (e.x >> 17) & 127;
        int pos = ex[r] + atomicAdd(&cur[r], 1);
        e.x &= 0x1FFFF;
        eLds[pos] = e;
    }
    __syncthreads();

    // gather: wave w handles local nodes w, w+4, ...
    const int wid = t >> 6, lane = t & 63;
    const int ovc = *oflow_cnt;                       // normally 0
    const float2 bv = *reinterpret_cast<const float2*>(bias + lane * 2);
    for (int ln = wid; ln < 128; ln += 4) {
        int node = bkt * 128 + ln;
        if (node >= N_NODES) break;
        const int j0 = ex[ln], j1 = ex[ln] + h[ln];
        float ax = 0.f, ay = 0.f, bx = 0.f, by = 0.f;
        float cx = 0.f, cy = 0.f, dx = 0.f, dy = 0.f;
        int j = j0;
        for (; j + 4 <= j1; j += 4) {
            int2 e0 = eLds[j],     e1 = eLds[j + 1];
            int2 e2 = eLds[j + 2], e3 = eLds[j + 3];
            unsigned u0 = *reinterpret_cast<const unsigned*>(HWb + (size_t)e0.x * D + lane * 2);
            unsigned u1 = *reinterpret_cast<const unsigned*>(HWb + (size_t)e1.x * D + lane * 2);
            unsigned u2 = *reinterpret_cast<const unsigned*>(HWb + (size_t)e2.x * D + lane * 2);
            unsigned u3 = *reinterpret_cast<const unsigned*>(HWb + (size_t)e3.x * D + lane * 2);
            float v0 = __int_as_float(e0.y), v1 = __int_as_float(e1.y);
            float v2 = __int_as_float(e2.y), v3 = __int_as_float(e3.y);
            ax += v0 * __uint_as_float(u0 << 16);
            ay += v0 * __uint_as_float(u0 & 0xffff0000u);
            bx += v1 * __uint_as_float(u1 << 16);
            by += v1 * __uint_as_float(u1 & 0xffff0000u);
            cx += v2 * __uint_as_float(u2 << 16);
            cy += v2 * __uint_as_float(u2 & 0xffff0000u);
            dx += v3 * __uint_as_float(u3 << 16);
            dy += v3 * __uint_as_float(u3 & 0xffff0000u);
        }
        for (; j < j1; ++j) {
            int2 e = eLds[j];
            unsigned u = *reinterpret_cast<const unsigned*>(HWb + (size_t)e.x * D + lane * 2);
            float v = __int_as_float(e.y);
            ax += v * __uint_as_float(u << 16);
            ay += v * __uint_as_float(u & 0xffff0000u);
        }
        // overflow backstop (ovc normally 0)
        for (int q = 0; q < ovc; ++q) {
            int4 e = oflow[q];
            if (e.x == node) {
                unsigned u = *reinterpret_cast<const unsigned*>(HWb + (size_t)e.y * D + lane * 2);
                float v = __int_as_float(e.z);
                ax += v * __uint_as_float(u << 16);
                ay += v * __uint_as_float(u & 0xffff0000u);
            }
        }
        float2 o;
        o.x = fmaxf((ax + bx) + (cx + dx) + bv.x, 0.f);
        o.y = fmaxf((ay + by) + (cy + dy) + bv.y, 0.f);
        *reinterpret_cast<float2*>(out + (size_t)node * D + lane * 2) = o;
    }
}

extern "C" void kernel_launch(void* const* d_in, const int* in_sizes, int n_in,
                              void* d_out, int out_size, void* d_ws, size_t ws_size,
                              hipStream_t stream) {
    const float* H    = (const float*)d_in[0];
    const float* vals = (const float*)d_in[1];
    const float* W    = (const float*)d_in[2];
    const float* b    = (const float*)d_in[3];
    const int*   src  = (const int*)d_in[4];
    const int*   dst  = (const int*)d_in[5];
    float* out = (float*)d_out;

    // workspace layout (~45 MB)
    unsigned short* HWb   = (unsigned short*)d_ws;                    // 25.6 MB
    unsigned short* Wfrag = HWb + (size_t)N_NODES * D;                // 32 KB
    int2* sedge_raw = (int2*)(Wfrag + 128 * 128);                     // 19.2 MB
    int*  ccursor   = (int*)(sedge_raw + (size_t)NBUCK * BCAP);       // NBUCK
    int*  oflow_cnt = ccursor + NBUCK;                                // 1
    int4* oflow     = (int4*)(oflow_cnt + 3);                         // 128 KB (16B aligned)

    hipMemsetAsync(ccursor, 0, (NBUCK + 1) * sizeof(int), stream);

    wconvert<<<64, 256, 0, stream>>>(W, Wfrag);
    gemm_mfma<<<(N_NODES + 63) / 64, 256, 0, stream>>>(H, Wfrag, HWb);
    fill_bucket<<<(N_EDGES + FCHUNK - 1) / FCHUNK, 256, 0, stream>>>(
        src, dst, vals, ccursor, sedge_raw, oflow, oflow_cnt);
    sort_gather<<<NBUCK, 256, 0, stream>>>(HWb, sedge_raw, ccursor, oflow,
                                           oflow_cnt, b, out);
}

// Round 6
// 134.187 us; speedup vs baseline: 20.4204x; 1.1770x over previous
//
#include <hip/hip_runtime.h>

#define N_NODES  100000
#define N_EDGES  1600000
#define D        128
#define NBUCK    1563         // ceil(100000 / 64): buckets of 64 nodes
#define BCAP     1536         // bucket capacity (avg 1024, sigma ~32 -> 16 sigma)
#define OCAP     8192         // overflow backstop capacity
#define FCHUNK   8192         // edges per WG in fill

typedef __attribute__((ext_vector_type(8))) short bf16x8;
typedef __attribute__((ext_vector_type(4))) float f32x4;

// f32 -> bf16 (round-to-nearest-even)
__device__ __forceinline__ unsigned short f2bf(float x) {
    unsigned u = __float_as_uint(x);
    u += 0x7fffu + ((u >> 16) & 1u);
    return (unsigned short)(u >> 16);
}

// ---------------------------------------------------------------------------
// 0) pack W into B-fragment order for mfma_f32_16x16x32_bf16 (unchanged)
// ---------------------------------------------------------------------------
__global__ __launch_bounds__(256) void wconvert(
    const float* __restrict__ W, unsigned short* __restrict__ Wfrag)
{
    int t = blockIdx.x * 256 + threadIdx.x;
    if (t >= 128 * 128) return;
    int k = t >> 7, n = t & 127;
    int c = n >> 4, cc = n & 15, ks = k >> 5, g = (k >> 3) & 3, j = k & 7;
    int lane = g * 16 + cc;
    Wfrag[(size_t)(((c * 4 + ks) * 64) + lane) * 8 + j] = f2bf(W[t]);
}

// ---------------------------------------------------------------------------
// 1) HW = H @ W via MFMA 16x16x32 bf16 (unchanged, verified R5)
// ---------------------------------------------------------------------------
__global__ __launch_bounds__(256) void gemm_mfma(
    const float* __restrict__ H, const unsigned short* __restrict__ Wfrag,
    unsigned short* __restrict__ HWb)
{
    const int wid  = threadIdx.x >> 6;
    const int lane = threadIdx.x & 63;
    const int row16 = blockIdx.x * 64 + wid * 16;
    const int g = lane >> 4;

    int arow = row16 + (lane & 15);
    if (arow >= N_NODES) arow = N_NODES - 1;

    f32x4 acc[8];
#pragma unroll
    for (int c = 0; c < 8; ++c) acc[c] = (f32x4){0.f, 0.f, 0.f, 0.f};

#pragma unroll
    for (int ks = 0; ks < 4; ++ks) {
        const float* ap = H + (size_t)arow * D + ks * 32 + g * 8;
        float4 a0 = *reinterpret_cast<const float4*>(ap);
        float4 a1 = *reinterpret_cast<const float4*>(ap + 4);
        bf16x8 af;
        af[0] = (short)f2bf(a0.x); af[1] = (short)f2bf(a0.y);
        af[2] = (short)f2bf(a0.z); af[3] = (short)f2bf(a0.w);
        af[4] = (short)f2bf(a1.x); af[5] = (short)f2bf(a1.y);
        af[6] = (short)f2bf(a1.z); af[7] = (short)f2bf(a1.w);
#pragma unroll
        for (int c = 0; c < 8; ++c) {
            bf16x8 bf = *reinterpret_cast<const bf16x8*>(
                Wfrag + (size_t)((c * 4 + ks) * 64 + lane) * 8);
            acc[c] = __builtin_amdgcn_mfma_f32_16x16x32_bf16(af, bf, acc[c], 0, 0, 0);
        }
    }

#pragma unroll
    for (int c = 0; c < 8; ++c) {
#pragma unroll
        for (int r = 0; r < 4; ++r) {
            int orow = row16 + g * 4 + r;
            if (orow < N_NODES)
                HWb[(size_t)orow * D + c * 16 + (lane & 15)] = f2bf(acc[c][r]);
        }
    }
}

// ---------------------------------------------------------------------------
// 2) fill fixed-stride buckets of 64 nodes (WG-aggregated reservation)
//    packed.x = dst | (src&63)<<17 ; packed.y = bits(val)
// ---------------------------------------------------------------------------
__global__ __launch_bounds__(256) void fill_bucket(
    const int* __restrict__ src, const int* __restrict__ dst,
    const float* __restrict__ vals, int* __restrict__ ccursor,
    int2* __restrict__ sedge_raw, int4* __restrict__ oflow,
    int* __restrict__ oflow_cnt)
{
    __shared__ int lhist[NBUCK];
    __shared__ int lbase[NBUCK];
    const int t = threadIdx.x;
    for (int i = t; i < NBUCK; i += 256) lhist[i] = 0;
    __syncthreads();
    const int e0 = blockIdx.x * FCHUNK;
    const int e1 = min(e0 + FCHUNK, N_EDGES);
    for (int e = e0 + t; e < e1; e += 256)
        atomicAdd(&lhist[src[e] >> 6], 1);
    __syncthreads();
    for (int i = t; i < NBUCK; i += 256) {
        int c = lhist[i];
        lbase[i] = c ? atomicAdd(&ccursor[i], c) : 0;
        lhist[i] = 0;
    }
    __syncthreads();
    for (int e = e0 + t; e < e1; e += 256) {
        int s = src[e];
        int bkt = s >> 6;
        int pos = lbase[bkt] + atomicAdd(&lhist[bkt], 1);
        if (pos < BCAP) {
            int2 p;
            p.x = dst[e] | ((s & 63) << 17);
            p.y = __float_as_int(vals[e]);
            sedge_raw[(size_t)bkt * BCAP + pos] = p;
        } else {
            int oc = atomicAdd(oflow_cnt, 1);
            if (oc < OCAP) oflow[oc] = make_int4(s, dst[e], __float_as_int(vals[e]), 0);
        }
    }
}

// ---------------------------------------------------------------------------
// 3) fused counting-sort (into LDS) + gather + bias + relu. One WG per bucket
//    of 64 nodes; wave-level shfl scan (no block-scan barriers).
// ---------------------------------------------------------------------------
__global__ __launch_bounds__(256) void sort_gather(
    const unsigned short* __restrict__ HWb, const int2* __restrict__ sedge_raw,
    const int* __restrict__ ccursor, const int4* __restrict__ oflow,
    const int* __restrict__ oflow_cnt, const float* __restrict__ bias,
    float* __restrict__ out)
{
    __shared__ int2 eLds[BCAP];     // 12 KB
    __shared__ int h[64];           // per-node counts
    __shared__ int ex[64];          // exclusive prefix
    __shared__ int cur[64];         // placement cursors
    const int bkt = blockIdx.x;
    const int t = threadIdx.x;
    const size_t base = (size_t)bkt * BCAP;
    const int cnt = min(ccursor[bkt], BCAP);

    if (t < 64) h[t] = 0;
    __syncthreads();
    // pass 1: histogram from global
    for (int j = t; j < cnt; j += 256)
        atomicAdd(&h[(sedge_raw[base + j].x >> 17) & 63], 1);
    __syncthreads();
    // exclusive scan over 64 counters: single wave, shfl_up
    if (t < 64) {
        int v = h[t];
        int x = v;
        for (int off = 1; off < 64; off <<= 1) {
            int y = __shfl_up(x, off);
            if (t >= off) x += y;
        }
        ex[t] = x - v;
        cur[t] = 0;
    }
    __syncthreads();
    // pass 2: place sorted into LDS (strip src bits)
    for (int j = t; j < cnt; j += 256) {
        int2 e = sedge_raw[base + j];
        int r = (e.x >> 17) & 63;
        int pos = ex[r] + atomicAdd(&cur[r], 1);
        e.x &= 0x1FFFF;
        eLds[pos] = e;
    }
    __syncthreads();

    // gather: wave w handles local nodes w, w+4, ...
    const int wid = t >> 6, lane = t & 63;
    const int ovc = *oflow_cnt;                       // normally 0
    const float2 bv = *reinterpret_cast<const float2*>(bias + lane * 2);
    for (int ln = wid; ln < 64; ln += 4) {
        int node = bkt * 64 + ln;
        if (node >= N_NODES) break;
        const int j0 = ex[ln], j1 = ex[ln] + h[ln];
        float ax = 0.f, ay = 0.f, bx = 0.f, by = 0.f;
        float cx = 0.f, cy = 0.f, dx = 0.f, dy = 0.f;
        int j = j0;
        for (; j + 4 <= j1; j += 4) {
            int2 e0 = eLds[j],     e1 = eLds[j + 1];
            int2 e2 = eLds[j + 2], e3 = eLds[j + 3];
            unsigned u0 = *reinterpret_cast<const unsigned*>(HWb + (size_t)e0.x * D + lane * 2);
            unsigned u1 = *reinterpret_cast<const unsigned*>(HWb + (size_t)e1.x * D + lane * 2);
            unsigned u2 = *reinterpret_cast<const unsigned*>(HWb + (size_t)e2.x * D + lane * 2);
            unsigned u3 = *reinterpret_cast<const unsigned*>(HWb + (size_t)e3.x * D + lane * 2);
            float v0 = __int_as_float(e0.y), v1 = __int_as_float(e1.y);
            float v2 = __int_as_float(e2.y), v3 = __int_as_float(e3.y);
            ax += v0 * __uint_as_float(u0 << 16);
            ay += v0 * __uint_as_float(u0 & 0xffff0000u);
            bx += v1 * __uint_as_float(u1 << 16);
            by += v1 * __uint_as_float(u1 & 0xffff0000u);
            cx += v2 * __uint_as_float(u2 << 16);
            cy += v2 * __uint_as_float(u2 & 0xffff0000u);
            dx += v3 * __uint_as_float(u3 << 16);
            dy += v3 * __uint_as_float(u3 & 0xffff0000u);
        }
        for (; j < j1; ++j) {
            int2 e = eLds[j];
            unsigned u = *reinterpret_cast<const unsigned*>(HWb + (size_t)e.x * D + lane * 2);
            float v = __int_as_float(e.y);
            ax += v * __uint_as_float(u << 16);
            ay += v * __uint_as_float(u & 0xffff0000u);
        }
        // overflow backstop (ovc normally 0)
        for (int q = 0; q < ovc; ++q) {
            int4 e = oflow[q];
            if (e.x == node) {
                unsigned u = *reinterpret_cast<const unsigned*>(HWb + (size_t)e.y * D + lane * 2);
                float v = __int_as_float(e.z);
                ax += v * __uint_as_float(u << 16);
                ay += v * __uint_as_float(u & 0xffff0000u);
            }
        }
        float2 o;
        o.x = fmaxf((ax + bx) + (cx + dx) + bv.x, 0.f);
        o.y = fmaxf((ay + by) + (cy + dy) + bv.y, 0.f);
        *reinterpret_cast<float2*>(out + (size_t)node * D + lane * 2) = o;
    }
}

extern "C" void kernel_launch(void* const* d_in, const int* in_sizes, int n_in,
                              void* d_out, int out_size, void* d_ws, size_t ws_size,
                              hipStream_t stream) {
    const float* H    = (const float*)d_in[0];
    const float* vals = (const float*)d_in[1];
    const float* W    = (const float*)d_in[2];
    const float* b    = (const float*)d_in[3];
    const int*   src  = (const int*)d_in[4];
    const int*   dst  = (const int*)d_in[5];
    float* out = (float*)d_out;

    // workspace layout (~45 MB)
    unsigned short* HWb   = (unsigned short*)d_ws;                    // 25.6 MB
    unsigned short* Wfrag = HWb + (size_t)N_NODES * D;                // 32 KB
    int2* sedge_raw = (int2*)(Wfrag + 128 * 128);                     // 19.2 MB
    int*  ccursor   = (int*)(sedge_raw + (size_t)NBUCK * BCAP);       // NBUCK
    int*  oflow_cnt = ccursor + NBUCK;                                // 1
    int4* oflow     = (int4*)(oflow_cnt + 3);                         // 128 KB

    hipMemsetAsync(ccursor, 0, (NBUCK + 1) * sizeof(int), stream);

    wconvert<<<64, 256, 0, stream>>>(W, Wfrag);
    gemm_mfma<<<(N_NODES + 63) / 64, 256, 0, stream>>>(H, Wfrag, HWb);
    fill_bucket<<<(N_EDGES + FCHUNK - 1) / FCHUNK, 256, 0, stream>>>(
        src, dst, vals, ccursor, sedge_raw, oflow, oflow_cnt);
    sort_gather<<<NBUCK, 256, 0, stream>>>(HWb, sedge_raw, ccursor, oflow,
                                           oflow_cnt, b, out);
}

// Round 7
// 128.078 us; speedup vs baseline: 21.3945x; 1.0477x over previous
//
#include <hip/hip_runtime.h>

#define N_NODES  100000
#define N_EDGES  1600000
#define D        128
#define NBUCK    3125         // 100000 / 32: buckets of 32 nodes (exact)
#define BCAP     768          // avg 512, sigma ~23 -> 11 sigma margin
#define OCAP     8192         // overflow backstop
#define FCHUNK   4096         // edges per fill block
#define GEMM_BLOCKS 1563      // ceil(100000 / 64)

typedef __attribute__((ext_vector_type(8))) short bf16x8;
typedef __attribute__((ext_vector_type(4))) float f32x4;

// f32 -> bf16 (round-to-nearest-even)
__device__ __forceinline__ unsigned short f2bf(float x) {
    unsigned u = __float_as_uint(x);
    u += 0x7fffu + ((u >> 16) & 1u);
    return (unsigned short)(u >> 16);
}

// ---------------------------------------------------------------------------
// mega kernel: blocks [0, GEMM_BLOCKS) do HW = H @ W (MFMA, W converted to
// LDS-resident bf16 fragments in-block); blocks [GEMM_BLOCKS, ...) fill
// fixed-stride 32-node buckets. Independent roles, complementary pipes.
// ---------------------------------------------------------------------------
__global__ __launch_bounds__(256) void mega(
    const float* __restrict__ H, const float* __restrict__ W,
    const int* __restrict__ src, const int* __restrict__ dst,
    const float* __restrict__ vals, unsigned short* __restrict__ HWb,
    int* __restrict__ ccursor, int2* __restrict__ sedge_raw,
    int4* __restrict__ oflow, int* __restrict__ oflow_cnt)
{
    __shared__ char smem[32768];
    const int t = threadIdx.x;

    if (blockIdx.x < GEMM_BLOCKS) {
        // ---- GEMM role ----
        short* wlds = (short*)smem;   // 16384 bf16 = 32 KB, fragment order
        // stage W -> LDS (coalesced loads, ds_write_b64 per 4-k column chunk)
        {
            const int n   = t & 127;
            const int kb0 = (t >> 7) * 4;        // 0 or 4
            const int c = n >> 4, cc = n & 15;
#pragma unroll
            for (int q = 0; q < 16; ++q) {
                int kbase = q * 8 + kb0;
                float w0 = W[(kbase + 0) * 128 + n];
                float w1 = W[(kbase + 1) * 128 + n];
                float w2 = W[(kbase + 2) * 128 + n];
                float w3 = W[(kbase + 3) * 128 + n];
                int ks = kbase >> 5, g = (kbase >> 3) & 3, j0 = kbase & 7;
                short4 pk;
                pk.x = (short)f2bf(w0);
                pk.y = (short)f2bf(w1);
                pk.z = (short)f2bf(w2);
                pk.w = (short)f2bf(w3);
                *reinterpret_cast<short4*>(
                    &wlds[(size_t)(((c * 4 + ks) * 64) + g * 16 + cc) * 8 + j0]) = pk;
            }
        }
        __syncthreads();

        const int wid  = t >> 6;
        const int lane = t & 63;
        const int row16 = blockIdx.x * 64 + wid * 16;
        const int g = lane >> 4;

        int arow = row16 + (lane & 15);
        if (arow >= N_NODES) arow = N_NODES - 1;   // clamp (dup read, never stored)

        f32x4 acc[8];
#pragma unroll
        for (int c = 0; c < 8; ++c) acc[c] = (f32x4){0.f, 0.f, 0.f, 0.f};

#pragma unroll
        for (int ks = 0; ks < 4; ++ks) {
            const float* ap = H + (size_t)arow * D + ks * 32 + g * 8;
            float4 a0 = *reinterpret_cast<const float4*>(ap);
            float4 a1 = *reinterpret_cast<const float4*>(ap + 4);
            bf16x8 af;
            af[0] = (short)f2bf(a0.x); af[1] = (short)f2bf(a0.y);
            af[2] = (short)f2bf(a0.z); af[3] = (short)f2bf(a0.w);
            af[4] = (short)f2bf(a1.x); af[5] = (short)f2bf(a1.y);
            af[6] = (short)f2bf(a1.z); af[7] = (short)f2bf(a1.w);
#pragma unroll
            for (int c = 0; c < 8; ++c) {
                bf16x8 bf = *reinterpret_cast<const bf16x8*>(
                    &wlds[(size_t)((c * 4 + ks) * 64 + lane) * 8]);
                acc[c] = __builtin_amdgcn_mfma_f32_16x16x32_bf16(af, bf, acc[c], 0, 0, 0);
            }
        }

#pragma unroll
        for (int c = 0; c < 8; ++c) {
#pragma unroll
            for (int r = 0; r < 4; ++r) {
                int orow = row16 + g * 4 + r;
                if (orow < N_NODES)
                    HWb[(size_t)orow * D + c * 16 + (lane & 15)] = f2bf(acc[c][r]);
            }
        }
    } else {
        // ---- FILL role ----
        int* lhist = (int*)smem;            // NBUCK ints
        int* lbase = lhist + NBUCK;         // NBUCK ints (25 KB total)
        for (int i = t; i < NBUCK; i += 256) lhist[i] = 0;
        __syncthreads();
        const int fb = blockIdx.x - GEMM_BLOCKS;
        const int e0 = fb * FCHUNK;
        const int e1 = min(e0 + FCHUNK, N_EDGES);
        for (int e = e0 + t; e < e1; e += 256)
            atomicAdd(&lhist[src[e] >> 5], 1);
        __syncthreads();
        for (int i = t; i < NBUCK; i += 256) {
            int c = lhist[i];
            lbase[i] = c ? atomicAdd(&ccursor[i], c) : 0;
            lhist[i] = 0;
        }
        __syncthreads();
        for (int e = e0 + t; e < e1; e += 256) {
            int s = src[e];
            int bkt = s >> 5;
            int pos = lbase[bkt] + atomicAdd(&lhist[bkt], 1);
            if (pos < BCAP) {
                int2 p;
                p.x = dst[e] | ((s & 31) << 17);
                p.y = __float_as_int(vals[e]);
                sedge_raw[(size_t)bkt * BCAP + pos] = p;
            } else {
                int oc = atomicAdd(oflow_cnt, 1);
                if (oc < OCAP) oflow[oc] = make_int4(s, dst[e], __float_as_int(vals[e]), 0);
            }
        }
    }
}

// ---------------------------------------------------------------------------
// fused counting-sort (register-staged, into LDS) + gather + bias + relu.
// One WG per 32-node bucket.
// ---------------------------------------------------------------------------
__global__ __launch_bounds__(256) void sort_gather(
    const unsigned short* __restrict__ HWb, const int2* __restrict__ sedge_raw,
    const int* __restrict__ ccursor, const int4* __restrict__ oflow,
    const int* __restrict__ oflow_cnt, const float* __restrict__ bias,
    float* __restrict__ out)
{
    __shared__ int2 eLds[BCAP];     // 6 KB
    __shared__ int h[32];
    __shared__ int ex[32];
    __shared__ int cur[32];
    const int bkt = blockIdx.x;
    const int t = threadIdx.x;
    const size_t base = (size_t)bkt * BCAP;
    const int cnt = min(ccursor[bkt], BCAP);

    if (t < 32) { h[t] = 0; }
    __syncthreads();

    // pass 1: load edges to registers + histogram (BCAP/256 = 3 per thread)
    int2 myE[3]; int myR[3];
#pragma unroll
    for (int q = 0; q < 3; ++q) {
        int j = t + q * 256;
        myR[q] = -1;
        if (j < cnt) {
            myE[q] = sedge_raw[base + j];
            myR[q] = (myE[q].x >> 17) & 31;
            atomicAdd(&h[myR[q]], 1);
        }
    }
    __syncthreads();
    // exclusive scan over 32 counters (first wave, shfl)
    if (t < 32) {
        int v = h[t];
        int x = v;
        for (int off = 1; off < 32; off <<= 1) {
            int y = __shfl_up(x, off);
            if (t >= off) x += y;
        }
        ex[t] = x - v;
        cur[t] = 0;
    }
    __syncthreads();
    // pass 2: place sorted into LDS from registers (strip src bits)
#pragma unroll
    for (int q = 0; q < 3; ++q) {
        if (myR[q] >= 0) {
            int pos = ex[myR[q]] + atomicAdd(&cur[myR[q]], 1);
            int2 e;
            e.x = myE[q].x & 0x1FFFF;
            e.y = myE[q].y;
            eLds[pos] = e;
        }
    }
    __syncthreads();

    // gather: wave w handles local nodes w, w+4, ...
    const int wid = t >> 6, lane = t & 63;
    const int ovc = *oflow_cnt;                       // normally 0
    const float2 bv = *reinterpret_cast<const float2*>(bias + lane * 2);
    for (int ln = wid; ln < 32; ln += 4) {
        int node = bkt * 32 + ln;
        const int j0 = ex[ln], j1 = ex[ln] + h[ln];
        float ax = 0.f, ay = 0.f, bx = 0.f, by = 0.f;
        float cx = 0.f, cy = 0.f, dx = 0.f, dy = 0.f;
        int j = j0;
        for (; j + 4 <= j1; j += 4) {
            int2 e0 = eLds[j],     e1 = eLds[j + 1];
            int2 e2 = eLds[j + 2], e3 = eLds[j + 3];
            unsigned u0 = *reinterpret_cast<const unsigned*>(HWb + (size_t)e0.x * D + lane * 2);
            unsigned u1 = *reinterpret_cast<const unsigned*>(HWb + (size_t)e1.x * D + lane * 2);
            unsigned u2 = *reinterpret_cast<const unsigned*>(HWb + (size_t)e2.x * D + lane * 2);
            unsigned u3 = *reinterpret_cast<const unsigned*>(HWb + (size_t)e3.x * D + lane * 2);
            float v0 = __int_as_float(e0.y), v1 = __int_as_float(e1.y);
            float v2 = __int_as_float(e2.y), v3 = __int_as_float(e3.y);
            ax += v0 * __uint_as_float(u0 << 16);
            ay += v0 * __uint_as_float(u0 & 0xffff0000u);
            bx += v1 * __uint_as_float(u1 << 16);
            by += v1 * __uint_as_float(u1 & 0xffff0000u);
            cx += v2 * __uint_as_float(u2 << 16);
            cy += v2 * __uint_as_float(u2 & 0xffff0000u);
            dx += v3 * __uint_as_float(u3 << 16);
            dy += v3 * __uint_as_float(u3 & 0xffff0000u);
        }
        for (; j < j1; ++j) {
            int2 e = eLds[j];
            unsigned u = *reinterpret_cast<const unsigned*>(HWb + (size_t)e.x * D + lane * 2);
            float v = __int_as_float(e.y);
            ax += v * __uint_as_float(u << 16);
            ay += v * __uint_as_float(u & 0xffff0000u);
        }
        // overflow backstop (ovc normally 0)
        for (int q = 0; q < ovc; ++q) {
            int4 e = oflow[q];
            if (e.x == node) {
                unsigned u = *reinterpret_cast<const unsigned*>(HWb + (size_t)e.y * D + lane * 2);
                float v = __int_as_float(e.z);
                ax += v * __uint_as_float(u << 16);
                ay += v * __uint_as_float(u & 0xffff0000u);
            }
        }
        float2 o;
        o.x = fmaxf((ax + bx) + (cx + dx) + bv.x, 0.f);
        o.y = fmaxf((ay + by) + (cy + dy) + bv.y, 0.f);
        *reinterpret_cast<float2*>(out + (size_t)node * D + lane * 2) = o;
    }
}

extern "C" void kernel_launch(void* const* d_in, const int* in_sizes, int n_in,
                              void* d_out, int out_size, void* d_ws, size_t ws_size,
                              hipStream_t stream) {
    const float* H    = (const float*)d_in[0];
    const float* vals = (const float*)d_in[1];
    const float* W    = (const float*)d_in[2];
    const float* b    = (const float*)d_in[3];
    const int*   src  = (const int*)d_in[4];
    const int*   dst  = (const int*)d_in[5];
    float* out = (float*)d_out;

    // workspace layout (~45 MB)
    unsigned short* HWb = (unsigned short*)d_ws;                      // 25.6 MB
    int2* sedge_raw = (int2*)(HWb + (size_t)N_NODES * D);             // 19.2 MB
    int*  ccursor   = (int*)(sedge_raw + (size_t)NBUCK * BCAP);       // NBUCK
    int*  oflow_cnt = ccursor + NBUCK;                                // 1
    int4* oflow     = (int4*)(oflow_cnt + 3);                         // 128 KB

    hipMemsetAsync(ccursor, 0, (NBUCK + 1) * sizeof(int), stream);

    const int FILL_BLOCKS = (N_EDGES + FCHUNK - 1) / FCHUNK;          // 391
    mega<<<GEMM_BLOCKS + FILL_BLOCKS, 256, 0, stream>>>(
        H, W, src, dst, vals, HWb, ccursor, sedge_raw, oflow, oflow_cnt);
    sort_gather<<<NBUCK, 256, 0, stream>>>(HWb, sedge_raw, ccursor, oflow,
                                           oflow_cnt, b, out);
}